// Round 4
// baseline (1640.294 us; speedup 1.0000x reference)
//
#include <hip/hip_runtime.h>

#define N_NODES 100000
#define N_EDGES 1600000
#define IN_C    128
#define HID     256
#define NLAYER  4

#define AS_STRIDE 264   // 256 + 8 pad: breaks 16-way bank aliasing on a-frag reads
#define BS_STRIDE 40    // 32 + 8 pad: breaks 8-way bank aliasing on b-frag reads

typedef __attribute__((ext_vector_type(8))) __bf16 bf16x8;
typedef __attribute__((ext_vector_type(4))) float  floatx4;

__device__ inline unsigned short f2b(float f) {
    unsigned u = __builtin_bit_cast(unsigned, f);
    return (unsigned short)((u + 0x7fffu + ((u >> 16) & 1u)) >> 16);
}
__device__ inline float b2f(unsigned short s) {
    unsigned u = ((unsigned)s) << 16;
    return __builtin_bit_cast(float, u);
}

// ---------------- degree / norm ----------------
__global__ void k_init(int* deg, int* fill, int n) {
    int i = blockIdx.x * blockDim.x + threadIdx.x;
    if (i < n) { deg[i] = 1; fill[i] = 0; }   // self-loop counts 1
}

__global__ void k_count(const int* __restrict__ col, int* deg, int e) {
    int i = blockIdx.x * blockDim.x + threadIdx.x;
    if (i < e) atomicAdd(&deg[col[i]], 1);
}

__global__ void k_dis(const int* __restrict__ deg, float* dis, int n) {
    int i = blockIdx.x * blockDim.x + threadIdx.x;
    if (i < n) dis[i] = rsqrtf((float)deg[i]);
}

// ---------------- exclusive scan of (deg-1) over N, single block ----------------
__global__ void k_scan(const int* __restrict__ deg, int* __restrict__ offs, int n) {
    __shared__ int wsum[17];
    __shared__ int carry;
    int lane = threadIdx.x & 63;
    int wid  = threadIdx.x >> 6;
    if (threadIdx.x == 0) carry = 0;
    __syncthreads();
    for (int base = 0; base < n; base += 4096) {
        int i0 = base + threadIdx.x * 4;
        int v[4]; int s = 0;
        #pragma unroll
        for (int t = 0; t < 4; ++t) { int i = i0 + t; v[t] = (i < n) ? (deg[i] - 1) : 0; s += v[t]; }
        int inc = s;
        #pragma unroll
        for (int off = 1; off < 64; off <<= 1) { int u = __shfl_up(inc, off); if (lane >= off) inc += u; }
        if (lane == 63) wsum[wid] = inc;
        __syncthreads();
        if (threadIdx.x == 0) {
            int r = 0;
            #pragma unroll
            for (int w = 0; w < 16; ++w) { int t = wsum[w]; wsum[w] = r; r += t; }
            wsum[16] = r;
        }
        __syncthreads();
        int boff = carry + wsum[wid] + (inc - s);
        #pragma unroll
        for (int t = 0; t < 4; ++t) { int i = i0 + t; if (i < n) offs[i] = boff; boff += v[t]; }
        __syncthreads();
        if (threadIdx.x == 0) carry += wsum[16];
        __syncthreads();
    }
    if (threadIdx.x == 0) offs[n] = carry;
}

__global__ void k_scatter(const int* __restrict__ row, const int* __restrict__ col,
                          const int* __restrict__ offs, int* fill, int* srcl, int e) {
    int i = blockIdx.x * blockDim.x + threadIdx.x;
    if (i < e) {
        int c = col[i];
        int p = offs[c] + atomicAdd(&fill[c], 1);
        srcl[p] = row[i];
    }
}

// ---------------- conversions ----------------
__global__ void k_f2b4(const float* __restrict__ src, unsigned short* __restrict__ dst, int n4) {
    int i = blockIdx.x * blockDim.x + threadIdx.x;
    if (i < n4) {
        float4 v = ((const float4*)src)[i];
        ushort4 o;
        o.x = f2b(v.x); o.y = f2b(v.y); o.z = f2b(v.z); o.w = f2b(v.w);
        ((ushort4*)dst)[i] = o;
    }
}

// W [K][Nn] fp32 row-major  ->  Wt [Nn][K] bf16
__global__ void k_wt(const float* __restrict__ W, unsigned short* __restrict__ Wt, int K, int Nn) {
    int idx = blockIdx.x * blockDim.x + threadIdx.x;
    if (idx < K * Nn) {
        int k = idx / Nn, n = idx % Nn;
        Wt[n * K + k] = f2b(W[idx]);
    }
}

// ---------------- MFMA GEMM: C[M,Nn] = A[M,K](bf16) @ Wt[Nn,K](bf16)^T ----------------
// MODE 0: enc   (+bias, *scale[row] if scale, store bf16)
// MODE 2: lin1  (+bias, relu,                 store fp32)
template<int MODE>
__global__ __launch_bounds__(256) void k_mm(
        const unsigned short* __restrict__ A,
        const unsigned short* __restrict__ Wt,
        const float* __restrict__ bias, const float* __restrict__ scale,
        void* __restrict__ Cout, int M, int K, int Nn) {
    __shared__ unsigned short As[128 * 32];
    __shared__ unsigned short Bs[128 * 32];
    const int tid  = threadIdx.x;
    const int lane = tid & 63;
    const int w    = tid >> 6;
    const int bm   = blockIdx.x * 128;
    const int bn   = blockIdx.y * 128;

    const int i0 = tid, i1 = tid + 256;
    const int r0 = i0 >> 2, r1 = i1 >> 2;
    const int q0 = i0 & 3,  q1 = i1 & 3;
    const int a_off0 = min(bm + r0, M - 1) * K + q0 * 8;
    const int a_off1 = min(bm + r1, M - 1) * K + q1 * 8;
    const int b_off0 = (bn + r0) * K + q0 * 8;
    const int b_off1 = (bn + r1) * K + q1 * 8;

    uint4 ra0, ra1, rb0, rb1;
    floatx4 acc[4][4];
    #pragma unroll
    for (int i = 0; i < 4; ++i)
        #pragma unroll
        for (int j = 0; j < 4; ++j)
            acc[i][j] = (floatx4){0.f, 0.f, 0.f, 0.f};

    const int wm = (w & 1) * 64;
    const int wn = (w >> 1) * 64;
    const int fm = lane & 15;
    const int fq = (lane >> 4) * 8;

    ra0 = *(const uint4*)(A  + a_off0);
    ra1 = *(const uint4*)(A  + a_off1);
    rb0 = *(const uint4*)(Wt + b_off0);
    rb1 = *(const uint4*)(Wt + b_off1);

    const int KT = K >> 5;
    for (int kt = 0; kt < KT; ++kt) {
        ((uint4*)As)[i0] = ra0; ((uint4*)As)[i1] = ra1;
        ((uint4*)Bs)[i0] = rb0; ((uint4*)Bs)[i1] = rb1;
        __syncthreads();
        if (kt + 1 < KT) {
            int k0 = (kt + 1) << 5;
            ra0 = *(const uint4*)(A  + a_off0 + k0);
            ra1 = *(const uint4*)(A  + a_off1 + k0);
            rb0 = *(const uint4*)(Wt + b_off0 + k0);
            rb1 = *(const uint4*)(Wt + b_off1 + k0);
        }
        bf16x8 af[4], bfr[4];
        #pragma unroll
        for (int i = 0; i < 4; ++i)
            af[i] = *(const bf16x8*)(const void*)(As + (wm + i * 16 + fm) * 32 + fq);
        #pragma unroll
        for (int j = 0; j < 4; ++j)
            bfr[j] = *(const bf16x8*)(const void*)(Bs + (wn + j * 16 + fm) * 32 + fq);
        #pragma unroll
        for (int i = 0; i < 4; ++i)
            #pragma unroll
            for (int j = 0; j < 4; ++j)
                acc[i][j] = __builtin_amdgcn_mfma_f32_16x16x32_bf16(af[i], bfr[j], acc[i][j], 0, 0, 0);
        __syncthreads();
    }

    const int quad = lane >> 4;
    #pragma unroll
    for (int i = 0; i < 4; ++i) {
        #pragma unroll
        for (int r = 0; r < 4; ++r) {
            int row = bm + wm + i * 16 + quad * 4 + r;
            if (row >= M) continue;
            float sc = (MODE == 0 && scale) ? scale[row] : 1.f;
            #pragma unroll
            for (int j = 0; j < 4; ++j) {
                int colg = bn + wn + j * 16 + fm;
                float v = acc[i][j][r] + bias[colg];
                if (MODE == 0) v *= sc;
                if (MODE == 2) v = fmaxf(v, 0.f);
                if (MODE == 2)
                    ((float*)Cout)[(size_t)row * Nn + colg] = v;
                else
                    ((unsigned short*)Cout)[(size_t)row * Nn + colg] = f2b(v);
            }
        }
    }
}

// ---------------- fused conv layer: gather(T)·dis -> @W -> +bias -> LN -> ReLU ----------------
// T = previous layer's h·dis table (bf16). Output: h' (·dis[node] if postscale) bf16.
__global__ __launch_bounds__(256, 3) void k_conv(
        const unsigned short* __restrict__ T,
        const unsigned short* __restrict__ Wt,       // [256 n][256 k] bf16
        const int* __restrict__ srcl, const int* __restrict__ offs,
        const float* __restrict__ dis,
        const float* __restrict__ cb, const float* __restrict__ g,
        const float* __restrict__ bt,
        const float* __restrict__ postscale,
        unsigned short* __restrict__ Hout, int n) {
    __shared__ unsigned short As[64 * AS_STRIDE];    // 33792 B
    __shared__ unsigned short Bs[256 * BS_STRIDE];   // 20480 B (reused for LN scratch)
    float* rsum = (float*)Bs;            // [64][4]
    float* rsq  = ((float*)Bs) + 256;    // [64][4]
    float* lnp  = ((float*)Bs) + 512;    // [64][2]

    const int tid  = threadIdx.x;
    const int lane = tid & 63;
    const int w    = tid >> 6;
    const int node0 = blockIdx.x * 64;
    const ushort4* T4 = (const ushort4*)T;

    // ---- gather phase: wave w owns local rows w*16 .. w*16+15
    for (int tt = 0; tt < 16; ++tt) {
        int tl = w * 16 + tt;
        int t  = node0 + tl;
        float a0=0,a1=0,a2=0,a3=0;
        if (t < n) {
            ushort4 sv = T4[(size_t)t * 64 + lane];   // self-loop (T pre-scaled by dis[src])
            a0 = b2f(sv.x); a1 = b2f(sv.y); a2 = b2f(sv.z); a3 = b2f(sv.w);
            float e0=0,e1=0,e2=0,e3=0, f0=0,f1=0,f2=0,f3=0, h0=0,h1=0,h2=0,h3=0;
            int p = offs[t], pe = offs[t + 1];
            for (; p + 3 < pe; p += 4) {
                int s0 = srcl[p], s1 = srcl[p+1], s2 = srcl[p+2], s3 = srcl[p+3];
                ushort4 v0 = T4[(size_t)s0 * 64 + lane];
                ushort4 v1 = T4[(size_t)s1 * 64 + lane];
                ushort4 v2 = T4[(size_t)s2 * 64 + lane];
                ushort4 v3 = T4[(size_t)s3 * 64 + lane];
                a0 += b2f(v0.x); a1 += b2f(v0.y); a2 += b2f(v0.z); a3 += b2f(v0.w);
                e0 += b2f(v1.x); e1 += b2f(v1.y); e2 += b2f(v1.z); e3 += b2f(v1.w);
                f0 += b2f(v2.x); f1 += b2f(v2.y); f2 += b2f(v2.z); f3 += b2f(v2.w);
                h0 += b2f(v3.x); h1 += b2f(v3.y); h2 += b2f(v3.z); h3 += b2f(v3.w);
            }
            for (; p < pe; ++p) {
                int s0 = srcl[p];
                ushort4 v0 = T4[(size_t)s0 * 64 + lane];
                a0 += b2f(v0.x); a1 += b2f(v0.y); a2 += b2f(v0.z); a3 += b2f(v0.w);
            }
            a0 += e0 + f0 + h0; a1 += e1 + f1 + h1; a2 += e2 + f2 + h2; a3 += e3 + f3 + h3;
            float dc = dis[t];
            a0 *= dc; a1 *= dc; a2 *= dc; a3 *= dc;
        }
        ushort4 o;
        o.x = f2b(a0); o.y = f2b(a1); o.z = f2b(a2); o.w = f2b(a3);
        *(ushort4*)(As + tl * AS_STRIDE + lane * 4) = o;
    }
    __syncthreads();

    // ---- MFMA phase: wave w computes all 64 rows x cols [w*64, w*64+64)
    floatx4 acc[4][4];
    #pragma unroll
    for (int i = 0; i < 4; ++i)
        #pragma unroll
        for (int j = 0; j < 4; ++j)
            acc[i][j] = (floatx4){0.f, 0.f, 0.f, 0.f};
    const int fm = lane & 15;
    const int q  = lane >> 4;

    for (int kt = 0; kt < 8; ++kt) {
        // stage Bs: 1024 uint4 loads, 4 per thread, coalesced-ish within rows
        #pragma unroll
        for (int s = 0; s < 4; ++s) {
            int L  = s * 256 + tid;
            int nn = L >> 2;
            int ko = (L & 3) * 8;
            uint4 v = *(const uint4*)(Wt + (size_t)nn * 256 + kt * 32 + ko);
            *(uint4*)(Bs + nn * BS_STRIDE + ko) = v;
        }
        __syncthreads();
        bf16x8 af[4], bfr[4];
        #pragma unroll
        for (int i = 0; i < 4; ++i)
            af[i] = *(const bf16x8*)(const void*)(As + (i * 16 + fm) * AS_STRIDE + kt * 32 + q * 8);
        #pragma unroll
        for (int j = 0; j < 4; ++j)
            bfr[j] = *(const bf16x8*)(const void*)(Bs + (w * 64 + j * 16 + fm) * BS_STRIDE + q * 8);
        #pragma unroll
        for (int i = 0; i < 4; ++i)
            #pragma unroll
            for (int j = 0; j < 4; ++j)
                acc[i][j] = __builtin_amdgcn_mfma_f32_16x16x32_bf16(af[i], bfr[j], acc[i][j], 0, 0, 0);
        __syncthreads();
    }

    // ---- epilogue: +bias, LN stats (full 256-col rows, block-local), ReLU, store
    float bias_v[4], gam[4], bet[4];
    #pragma unroll
    for (int j = 0; j < 4; ++j) {
        int col = w * 64 + j * 16 + fm;
        bias_v[j] = cb[col]; gam[j] = g[col]; bet[j] = bt[col];
    }
    #pragma unroll
    for (int i = 0; i < 4; ++i) {
        #pragma unroll
        for (int r = 0; r < 4; ++r) {
            float s = 0.f, ss = 0.f;
            #pragma unroll
            for (int j = 0; j < 4; ++j) {
                float v = acc[i][j][r] + bias_v[j];
                acc[i][j][r] = v;
                s += v; ss += v * v;
            }
            #pragma unroll
            for (int off = 1; off < 16; off <<= 1) {
                s  += __shfl_xor(s,  off);
                ss += __shfl_xor(ss, off);
            }
            if (fm == 0) {
                int m = i * 16 + q * 4 + r;
                rsum[m * 4 + w] = s;
                rsq [m * 4 + w] = ss;
            }
        }
    }
    __syncthreads();
    if (tid < 64) {
        float s  = rsum[tid*4] + rsum[tid*4+1] + rsum[tid*4+2] + rsum[tid*4+3];
        float ss = rsq [tid*4] + rsq [tid*4+1] + rsq [tid*4+2] + rsq [tid*4+3];
        float mu  = s * (1.f / 256.f);
        float var = ss * (1.f / 256.f) - mu * mu;
        lnp[tid * 2]     = mu;
        lnp[tid * 2 + 1] = rsqrtf(var + 1e-5f);
    }
    __syncthreads();
    #pragma unroll
    for (int i = 0; i < 4; ++i) {
        #pragma unroll
        for (int r = 0; r < 4; ++r) {
            int m  = i * 16 + q * 4 + r;
            int gm = node0 + m;
            if (gm >= n) continue;
            float mu  = lnp[m * 2];
            float inv = lnp[m * 2 + 1];
            float ps  = postscale ? postscale[gm] : 1.f;
            #pragma unroll
            for (int j = 0; j < 4; ++j) {
                float v = fmaxf(fmaf((acc[i][j][r] - mu) * inv, gam[j], bet[j]), 0.f);
                Hout[(size_t)gm * 256 + w * 64 + j * 16 + fm] = f2b(v * ps);
            }
        }
    }
}

// ---------------- lin2: out[node] = dot(hid1[node,:128], w2) + b2 ----------------
__global__ void k_lin2(const float* __restrict__ hid, const float* __restrict__ w2,
                       const float* __restrict__ b2, float* __restrict__ out, int n) {
    int gtid = blockIdx.x * blockDim.x + threadIdx.x;
    int node = gtid >> 6;
    int lane = threadIdx.x & 63;
    if (node >= n) return;
    float2 h = ((const float2*)hid)[node * 64 + lane];
    float2 wv = ((const float2*)w2)[lane];
    float r = h.x * wv.x + h.y * wv.y;
    #pragma unroll
    for (int off = 32; off; off >>= 1) r += __shfl_down(r, off);
    if (lane == 0) out[node] = r + b2[0];
}

extern "C" void kernel_launch(void* const* d_in, const int* in_sizes, int n_in,
                              void* d_out, int out_size, void* d_ws, size_t ws_size,
                              hipStream_t stream) {
    const float* x      = (const float*)d_in[0];
    const int*   ei     = (const int*)d_in[1];     // (2,E) int32
    const float* enc_w  = (const float*)d_in[2];
    const float* enc_b  = (const float*)d_in[3];
    const float* conv_w = (const float*)d_in[4];
    const float* conv_b = (const float*)d_in[5];
    const float* ln_g   = (const float*)d_in[6];
    const float* ln_b   = (const float*)d_in[7];
    const float* w1     = (const float*)d_in[8];
    const float* b1     = (const float*)d_in[9];
    const float* w2     = (const float*)d_in[10];
    const float* b2     = (const float*)d_in[11];
    float* out = (float*)d_out;

    char* ws = (char*)d_ws;
    size_t off = 0;
    auto alloc = [&](size_t bytes) -> void* {
        void* p = ws + off;
        off = (off + bytes + 255) & ~(size_t)255;
        return p;
    };
    int*   deg  = (int*)alloc((size_t)N_NODES * 4);
    int*   fill = (int*)alloc((size_t)N_NODES * 4);
    int*   offs = (int*)alloc((size_t)(N_NODES + 1) * 4);
    int*   srcl = (int*)alloc((size_t)N_EDGES * 4);
    float* dis  = (float*)alloc((size_t)N_NODES * 4);
    unsigned short* hbA = (unsigned short*)alloc((size_t)N_NODES * HID * 2);
    unsigned short* hbB = (unsigned short*)alloc((size_t)N_NODES * HID * 2);
    // region: xb (bf16 x) then hid1 (fp32), lifetimes disjoint
    char* R2 = (char*)alloc((size_t)N_NODES * (HID / 2) * 4);
    unsigned short* xb   = (unsigned short*)R2;
    float*          hid1 = (float*)R2;
    unsigned short* enc_t  = (unsigned short*)alloc((size_t)IN_C * HID * 2);
    unsigned short* conv_t = (unsigned short*)alloc((size_t)NLAYER * HID * HID * 2);
    unsigned short* lin1_t = (unsigned short*)alloc((size_t)HID * (HID / 2) * 2);

    const int* row = ei;             // sources
    const int* col = ei + N_EDGES;   // targets

    int nb = (N_NODES + 255) / 256;
    int eb = (N_EDGES + 255) / 256;

    k_init<<<nb, 256, 0, stream>>>(deg, fill, N_NODES);
    k_count<<<eb, 256, 0, stream>>>(col, deg, N_EDGES);
    k_dis<<<nb, 256, 0, stream>>>(deg, dis, N_NODES);
    k_scan<<<1, 1024, 0, stream>>>(deg, offs, N_NODES);
    k_scatter<<<eb, 256, 0, stream>>>(row, col, offs, fill, srcl, N_EDGES);

    // conversions
    int xn4 = N_NODES * IN_C / 4;
    k_f2b4<<<(xn4 + 255) / 256, 256, 0, stream>>>(x, xb, xn4);
    k_wt<<<(IN_C * HID + 255) / 256, 256, 0, stream>>>(enc_w, enc_t, IN_C, HID);
    for (int l = 0; l < NLAYER; ++l)
        k_wt<<<(HID * HID + 255) / 256, 256, 0, stream>>>(
            conv_w + (size_t)l * HID * HID, conv_t + (size_t)l * HID * HID, HID, HID);
    k_wt<<<(HID * (HID / 2) + 255) / 256, 256, 0, stream>>>(w1, lin1_t, HID, HID / 2);

    // encoder: T0 = bf16((x @ enc_w + enc_b) * dis[row])  -> hbA
    {
        dim3 g((N_NODES + 127) / 128, HID / 128);
        k_mm<0><<<g, 256, 0, stream>>>(xb, enc_t, enc_b, dis, hbA, N_NODES, IN_C, HID);
    }

    // fused conv layers, ping-pong hbA <-> hbB; last layer stores plain h (no postscale)
    {
        int cgrid = (N_NODES + 63) / 64;
        unsigned short* src = hbA;
        unsigned short* dst = hbB;
        for (int l = 0; l < NLAYER; ++l) {
            const float* ps = (l == NLAYER - 1) ? nullptr : dis;
            k_conv<<<cgrid, 256, 0, stream>>>(
                src, conv_t + (size_t)l * HID * HID, srcl, offs, dis,
                conv_b + l * HID, ln_g + l * HID, ln_b + l * HID, ps, dst, N_NODES);
            unsigned short* tmp = src; src = dst; dst = tmp;
        }
        // after 4 layers result is in hbA (4 swaps)
    }

    // head
    {
        dim3 g((N_NODES + 127) / 128, 1);
        k_mm<2><<<g, 256, 0, stream>>>(hbA, lin1_t, b1, nullptr, hid1, N_NODES, HID, HID / 2);
    }
    k_lin2<<<(N_NODES * 64 + 255) / 256, 256, 0, stream>>>(hid1, w2, b2, out, N_NODES);
}

// Round 6
// 1048.399 us; speedup vs baseline: 1.5646x; 1.5646x over previous
//
#include <hip/hip_runtime.h>

#define N_NODES 100000
#define N_EDGES 1600000
#define IN_C    128
#define HID     256
#define NLAYER  4

typedef __attribute__((ext_vector_type(8))) __bf16 bf16x8;
typedef __attribute__((ext_vector_type(4))) float  floatx4;

__device__ inline unsigned short f2b(float f) {
    unsigned u = __builtin_bit_cast(unsigned, f);
    return (unsigned short)((u + 0x7fffu + ((u >> 16) & 1u)) >> 16);
}
__device__ inline float b2f(unsigned short s) {
    unsigned u = ((unsigned)s) << 16;
    return __builtin_bit_cast(float, u);
}
// unpack+accumulate 8 bf16 (uint4) into fp32[8]
__device__ inline void acc8(float* a, uint4 v) {
    unsigned wds[4] = {v.x, v.y, v.z, v.w};
    #pragma unroll
    for (int k = 0; k < 4; ++k) {
        a[2*k]   += __builtin_bit_cast(float, wds[k] << 16);
        a[2*k+1] += __builtin_bit_cast(float, wds[k] & 0xffff0000u);
    }
}

// ---------------- degree / norm ----------------
__global__ void k_init(int* deg, int* fill, int n) {
    int i = blockIdx.x * blockDim.x + threadIdx.x;
    if (i < n) { deg[i] = 1; fill[i] = 0; }   // self-loop counts 1
}

__global__ void k_count(const int* __restrict__ col, int* deg, int e) {
    int i = blockIdx.x * blockDim.x + threadIdx.x;
    if (i < e) atomicAdd(&deg[col[i]], 1);
}

__global__ void k_dis(const int* __restrict__ deg, float* dis, int n) {
    int i = blockIdx.x * blockDim.x + threadIdx.x;
    if (i < n) dis[i] = rsqrtf((float)deg[i]);
}

// ---------------- exclusive scan of (deg-1) over N, single block ----------------
__global__ void k_scan(const int* __restrict__ deg, int* __restrict__ offs, int n) {
    __shared__ int wsum[17];
    __shared__ int carry;
    int lane = threadIdx.x & 63;
    int wid  = threadIdx.x >> 6;
    if (threadIdx.x == 0) carry = 0;
    __syncthreads();
    for (int base = 0; base < n; base += 4096) {
        int i0 = base + threadIdx.x * 4;
        int v[4]; int s = 0;
        #pragma unroll
        for (int t = 0; t < 4; ++t) { int i = i0 + t; v[t] = (i < n) ? (deg[i] - 1) : 0; s += v[t]; }
        int inc = s;
        #pragma unroll
        for (int off = 1; off < 64; off <<= 1) { int u = __shfl_up(inc, off); if (lane >= off) inc += u; }
        if (lane == 63) wsum[wid] = inc;
        __syncthreads();
        if (threadIdx.x == 0) {
            int r = 0;
            #pragma unroll
            for (int w = 0; w < 16; ++w) { int t = wsum[w]; wsum[w] = r; r += t; }
            wsum[16] = r;
        }
        __syncthreads();
        int boff = carry + wsum[wid] + (inc - s);
        #pragma unroll
        for (int t = 0; t < 4; ++t) { int i = i0 + t; if (i < n) offs[i] = boff; boff += v[t]; }
        __syncthreads();
        if (threadIdx.x == 0) carry += wsum[16];
        __syncthreads();
    }
    if (threadIdx.x == 0) offs[n] = carry;
}

__global__ void k_scatter(const int* __restrict__ row, const int* __restrict__ col,
                          const int* __restrict__ offs, int* fill, int* srcl, int e) {
    int i = blockIdx.x * blockDim.x + threadIdx.x;
    if (i < e) {
        int c = col[i];
        int p = offs[c] + atomicAdd(&fill[c], 1);
        srcl[p] = row[i];
    }
}

// ---------------- conversions ----------------
__global__ void k_f2b4(const float* __restrict__ src, unsigned short* __restrict__ dst, int n4) {
    int i = blockIdx.x * blockDim.x + threadIdx.x;
    if (i < n4) {
        float4 v = ((const float4*)src)[i];
        ushort4 o;
        o.x = f2b(v.x); o.y = f2b(v.y); o.z = f2b(v.z); o.w = f2b(v.w);
        ((ushort4*)dst)[i] = o;
    }
}

// W [K][Nn] fp32 row-major  ->  Wt [Nn][K] bf16
__global__ void k_wt(const float* __restrict__ W, unsigned short* __restrict__ Wt, int K, int Nn) {
    int idx = blockIdx.x * blockDim.x + threadIdx.x;
    if (idx < K * Nn) {
        int k = idx / Nn, n = idx % Nn;
        Wt[n * K + k] = f2b(W[idx]);
    }
}

// ---------------- MFMA GEMM: C[M,Nn] = A[M,K](bf16) @ Wt[Nn,K](bf16)^T ----------------
// MODE 0: enc   (+bias, *scale[row] if scale, store bf16)
// MODE 1: conv  (*scale[row],                 store bf16)
template<int MODE>
__global__ __launch_bounds__(256) void k_mm(
        const unsigned short* __restrict__ A,
        const unsigned short* __restrict__ Wt,
        const float* __restrict__ bias, const float* __restrict__ scale,
        void* __restrict__ Cout, int M, int K, int Nn) {
    __shared__ unsigned short As[128 * 32];
    __shared__ unsigned short Bs[128 * 32];
    const int tid  = threadIdx.x;
    const int lane = tid & 63;
    const int w    = tid >> 6;
    const int bm   = blockIdx.x * 128;
    const int bn   = blockIdx.y * 128;

    const int i0 = tid, i1 = tid + 256;
    const int r0 = i0 >> 2, r1 = i1 >> 2;
    const int q0 = i0 & 3,  q1 = i1 & 3;
    const int a_off0 = min(bm + r0, M - 1) * K + q0 * 8;
    const int a_off1 = min(bm + r1, M - 1) * K + q1 * 8;
    const int b_off0 = (bn + r0) * K + q0 * 8;
    const int b_off1 = (bn + r1) * K + q1 * 8;

    uint4 ra0, ra1, rb0, rb1;
    floatx4 acc[4][4];
    #pragma unroll
    for (int i = 0; i < 4; ++i)
        #pragma unroll
        for (int j = 0; j < 4; ++j)
            acc[i][j] = (floatx4){0.f, 0.f, 0.f, 0.f};

    const int wm = (w & 1) * 64;
    const int wn = (w >> 1) * 64;
    const int fm = lane & 15;
    const int fq = (lane >> 4) * 8;

    ra0 = *(const uint4*)(A  + a_off0);
    ra1 = *(const uint4*)(A  + a_off1);
    rb0 = *(const uint4*)(Wt + b_off0);
    rb1 = *(const uint4*)(Wt + b_off1);

    const int KT = K >> 5;
    for (int kt = 0; kt < KT; ++kt) {
        ((uint4*)As)[i0] = ra0; ((uint4*)As)[i1] = ra1;
        ((uint4*)Bs)[i0] = rb0; ((uint4*)Bs)[i1] = rb1;
        __syncthreads();
        if (kt + 1 < KT) {
            int k0 = (kt + 1) << 5;
            ra0 = *(const uint4*)(A  + a_off0 + k0);
            ra1 = *(const uint4*)(A  + a_off1 + k0);
            rb0 = *(const uint4*)(Wt + b_off0 + k0);
            rb1 = *(const uint4*)(Wt + b_off1 + k0);
        }
        bf16x8 af[4], bfr[4];
        #pragma unroll
        for (int i = 0; i < 4; ++i)
            af[i] = *(const bf16x8*)(const void*)(As + (wm + i * 16 + fm) * 32 + fq);
        #pragma unroll
        for (int j = 0; j < 4; ++j)
            bfr[j] = *(const bf16x8*)(const void*)(Bs + (wn + j * 16 + fm) * 32 + fq);
        #pragma unroll
        for (int i = 0; i < 4; ++i)
            #pragma unroll
            for (int j = 0; j < 4; ++j)
                acc[i][j] = __builtin_amdgcn_mfma_f32_16x16x32_bf16(af[i], bfr[j], acc[i][j], 0, 0, 0);
        __syncthreads();
    }

    const int quad = lane >> 4;
    #pragma unroll
    for (int i = 0; i < 4; ++i) {
        #pragma unroll
        for (int r = 0; r < 4; ++r) {
            int row = bm + wm + i * 16 + quad * 4 + r;
            if (row >= M) continue;
            float sc = scale ? scale[row] : 1.f;
            #pragma unroll
            for (int j = 0; j < 4; ++j) {
                int colg = bn + wn + j * 16 + fm;
                float v = acc[i][j][r];
                if (MODE == 0) v += bias[colg];
                v *= sc;
                ((unsigned short*)Cout)[(size_t)row * Nn + colg] = f2b(v);
            }
        }
    }
}

// ---------------- fused head: out = relu(h@w1+b1)@w2 + b2, MFMA, BN=128=full width ----------------
__global__ __launch_bounds__(256) void k_head(
        const unsigned short* __restrict__ A,     // h bf16 [M,256]
        const unsigned short* __restrict__ Wt,    // lin1^T bf16 [128][256]
        const float* __restrict__ b1, const float* __restrict__ w2,
        const float* __restrict__ b2, float* __restrict__ out, int M) {
    const int K = 256;
    __shared__ unsigned short As[128 * 32];
    __shared__ unsigned short Bs[128 * 32];
    const int tid  = threadIdx.x;
    const int lane = tid & 63;
    const int w    = tid >> 6;
    const int bm   = blockIdx.x * 128;

    const int i0 = tid, i1 = tid + 256;
    const int r0 = i0 >> 2, r1 = i1 >> 2;
    const int q0 = i0 & 3,  q1 = i1 & 3;
    const int a_off0 = min(bm + r0, M - 1) * K + q0 * 8;
    const int a_off1 = min(bm + r1, M - 1) * K + q1 * 8;
    const int b_off0 = r0 * K + q0 * 8;
    const int b_off1 = r1 * K + q1 * 8;

    uint4 ra0, ra1, rb0, rb1;
    floatx4 acc[4][4];
    #pragma unroll
    for (int i = 0; i < 4; ++i)
        #pragma unroll
        for (int j = 0; j < 4; ++j)
            acc[i][j] = (floatx4){0.f, 0.f, 0.f, 0.f};

    const int wm = (w & 1) * 64;
    const int wn = (w >> 1) * 64;
    const int fm = lane & 15;
    const int fq = (lane >> 4) * 8;

    ra0 = *(const uint4*)(A  + a_off0);
    ra1 = *(const uint4*)(A  + a_off1);
    rb0 = *(const uint4*)(Wt + b_off0);
    rb1 = *(const uint4*)(Wt + b_off1);

    for (int kt = 0; kt < 8; ++kt) {
        ((uint4*)As)[i0] = ra0; ((uint4*)As)[i1] = ra1;
        ((uint4*)Bs)[i0] = rb0; ((uint4*)Bs)[i1] = rb1;
        __syncthreads();
        if (kt + 1 < 8) {
            int k0 = (kt + 1) << 5;
            ra0 = *(const uint4*)(A  + a_off0 + k0);
            ra1 = *(const uint4*)(A  + a_off1 + k0);
            rb0 = *(const uint4*)(Wt + b_off0 + k0);
            rb1 = *(const uint4*)(Wt + b_off1 + k0);
        }
        bf16x8 af[4], bfr[4];
        #pragma unroll
        for (int i = 0; i < 4; ++i)
            af[i] = *(const bf16x8*)(const void*)(As + (wm + i * 16 + fm) * 32 + fq);
        #pragma unroll
        for (int j = 0; j < 4; ++j)
            bfr[j] = *(const bf16x8*)(const void*)(Bs + (wn + j * 16 + fm) * 32 + fq);
        #pragma unroll
        for (int i = 0; i < 4; ++i)
            #pragma unroll
            for (int j = 0; j < 4; ++j)
                acc[i][j] = __builtin_amdgcn_mfma_f32_16x16x32_bf16(af[i], bfr[j], acc[i][j], 0, 0, 0);
        __syncthreads();
    }

    // epilogue: relu(acc + b1) dot w2, reduce into out
    float* red = (float*)As;   // 256 floats, safe after final barrier
    const int q = lane >> 4;
    float b1v[4], w2v[4];
    #pragma unroll
    for (int j = 0; j < 4; ++j) {
        int col = wn + j * 16 + fm;
        b1v[j] = b1[col]; w2v[j] = w2[col];
    }
    #pragma unroll
    for (int i = 0; i < 4; ++i) {
        #pragma unroll
        for (int r = 0; r < 4; ++r) {
            float s = 0.f;
            #pragma unroll
            for (int j = 0; j < 4; ++j)
                s += fmaxf(acc[i][j][r] + b1v[j], 0.f) * w2v[j];
            #pragma unroll
            for (int off = 1; off < 16; off <<= 1) s += __shfl_xor(s, off);
            if (fm == 0) {
                int m = wm + i * 16 + q * 4 + r;
                red[m * 2 + (wn >> 6)] = s;
            }
        }
    }
    __syncthreads();
    if (tid < 128) {
        int row = bm + tid;
        if (row < M) out[row] = red[tid * 2] + red[tid * 2 + 1] + b2[0];
    }
}

// ---------------- aggregation + bias + LayerNorm + ReLU, one wave per node ----------------
// 2 edges per wave: lanes 0-31 = edge p, lanes 32-63 = edge p+1, 16B/lane.
__global__ void k_agg(const unsigned short* __restrict__ hw, const int* __restrict__ srcl,
                      const int* __restrict__ offs, const float* __restrict__ dis,
                      const float* __restrict__ cb, const float* __restrict__ g,
                      const float* __restrict__ bt, unsigned short* __restrict__ hout, int n) {
    int gtid = blockIdx.x * blockDim.x + threadIdx.x;
    int node = gtid >> 6;
    int lane = threadIdx.x & 63;
    if (node >= n) return;
    const int half = lane >> 5;
    const int sub  = lane & 31;
    const uint4* T = (const uint4*)hw;    // row = 32 x uint4 (512 B)

    float a[8] = {0,0,0,0,0,0,0,0};
    float c[8] = {0,0,0,0,0,0,0,0};
    if (half == 0) {
        uint4 v = T[(size_t)node * 32 + sub];   // self-loop (pre-scaled by dis[src])
        acc8(a, v);
    }
    int p = offs[node], pe = offs[node + 1];
    for (; p + 3 < pe; p += 4) {
        int s0 = srcl[p], s1 = srcl[p + 1], s2 = srcl[p + 2], s3 = srcl[p + 3];
        int sa = half ? s1 : s0;
        int sb = half ? s3 : s2;
        uint4 va = T[(size_t)sa * 32 + sub];
        uint4 vb = T[(size_t)sb * 32 + sub];
        acc8(a, va);
        acc8(c, vb);
    }
    for (; p < pe; p += 2) {
        int s0 = srcl[p];
        int s1 = (p + 1 < pe) ? srcl[p + 1] : -1;
        int sa = half ? s1 : s0;
        if (sa >= 0) {
            uint4 v = T[(size_t)sa * 32 + sub];
            acc8(a, v);
        }
    }
    #pragma unroll
    for (int j = 0; j < 8; ++j) {
        a[j] += c[j];
        a[j] += __shfl_xor(a[j], 32);   // combine edge-parity halves
    }
    // lanes 0-31 (and duplicated 32-63) now hold the full aggregate; features f = sub*8+j
    float dc = dis[node];
    const float4* cb4 = (const float4*)cb;
    const float4* g4  = (const float4*)g;
    const float4* bt4 = (const float4*)bt;
    float4 cba = cb4[sub * 2], cbb = cb4[sub * 2 + 1];
    float h[8];
    h[0] = fmaf(a[0], dc, cba.x); h[1] = fmaf(a[1], dc, cba.y);
    h[2] = fmaf(a[2], dc, cba.z); h[3] = fmaf(a[3], dc, cba.w);
    h[4] = fmaf(a[4], dc, cbb.x); h[5] = fmaf(a[5], dc, cbb.y);
    h[6] = fmaf(a[6], dc, cbb.z); h[7] = fmaf(a[7], dc, cbb.w);
    float s = 0.f, sq = 0.f;
    #pragma unroll
    for (int j = 0; j < 8; ++j) { s += h[j]; sq += h[j] * h[j]; }
    #pragma unroll
    for (int off = 1; off < 32; off <<= 1) { s += __shfl_xor(s, off); sq += __shfl_xor(sq, off); }
    float mu  = s * (1.f / 256.f);
    float var = sq * (1.f / 256.f) - mu * mu;
    float inv = rsqrtf(var + 1e-5f);
    if (half == 0) {
        float4 ga = g4[sub * 2], gb = g4[sub * 2 + 1];
        float4 ba = bt4[sub * 2], bb = bt4[sub * 2 + 1];
        float gv[8] = {ga.x, ga.y, ga.z, ga.w, gb.x, gb.y, gb.z, gb.w};
        float bv[8] = {ba.x, ba.y, ba.z, ba.w, bb.x, bb.y, bb.z, bb.w};
        unsigned short o[8];
        #pragma unroll
        for (int j = 0; j < 8; ++j)
            o[j] = f2b(fmaxf(fmaf((h[j] - mu) * inv, gv[j], bv[j]), 0.f));
        uint4 st;
        st.x = (unsigned)o[0] | ((unsigned)o[1] << 16);
        st.y = (unsigned)o[2] | ((unsigned)o[3] << 16);
        st.z = (unsigned)o[4] | ((unsigned)o[5] << 16);
        st.w = (unsigned)o[6] | ((unsigned)o[7] << 16);
        ((uint4*)hout)[(size_t)node * 32 + sub] = st;
    }
}

extern "C" void kernel_launch(void* const* d_in, const int* in_sizes, int n_in,
                              void* d_out, int out_size, void* d_ws, size_t ws_size,
                              hipStream_t stream) {
    const float* x      = (const float*)d_in[0];
    const int*   ei     = (const int*)d_in[1];     // (2,E) int32
    const float* enc_w  = (const float*)d_in[2];
    const float* enc_b  = (const float*)d_in[3];
    const float* conv_w = (const float*)d_in[4];
    const float* conv_b = (const float*)d_in[5];
    const float* ln_g   = (const float*)d_in[6];
    const float* ln_b   = (const float*)d_in[7];
    const float* w1     = (const float*)d_in[8];
    const float* b1     = (const float*)d_in[9];
    const float* w2     = (const float*)d_in[10];
    const float* b2     = (const float*)d_in[11];
    float* out = (float*)d_out;

    char* ws = (char*)d_ws;
    size_t off = 0;
    auto alloc = [&](size_t bytes) -> void* {
        void* p = ws + off;
        off = (off + bytes + 255) & ~(size_t)255;
        return p;
    };
    int*   deg  = (int*)alloc((size_t)N_NODES * 4);
    int*   fill = (int*)alloc((size_t)N_NODES * 4);
    int*   offs = (int*)alloc((size_t)(N_NODES + 1) * 4);
    int*   srcl = (int*)alloc((size_t)N_EDGES * 4);
    float* dis  = (float*)alloc((size_t)N_NODES * 4);
    unsigned short* hb = (unsigned short*)alloc((size_t)N_NODES * HID * 2);   // h, bf16
    unsigned short* hw = (unsigned short*)alloc((size_t)N_NODES * HID * 2);   // hw, bf16
    unsigned short* xb = (unsigned short*)alloc((size_t)N_NODES * IN_C * 2);
    unsigned short* enc_t  = (unsigned short*)alloc((size_t)IN_C * HID * 2);
    unsigned short* conv_t = (unsigned short*)alloc((size_t)NLAYER * HID * HID * 2);
    unsigned short* lin1_t = (unsigned short*)alloc((size_t)HID * (HID / 2) * 2);

    const int* row = ei;             // sources
    const int* col = ei + N_EDGES;   // targets

    int nb = (N_NODES + 255) / 256;
    int eb = (N_EDGES + 255) / 256;

    k_init<<<nb, 256, 0, stream>>>(deg, fill, N_NODES);
    k_count<<<eb, 256, 0, stream>>>(col, deg, N_EDGES);
    k_dis<<<nb, 256, 0, stream>>>(deg, dis, N_NODES);
    k_scan<<<1, 1024, 0, stream>>>(deg, offs, N_NODES);
    k_scatter<<<eb, 256, 0, stream>>>(row, col, offs, fill, srcl, N_EDGES);

    // conversions
    int xn4 = N_NODES * IN_C / 4;
    k_f2b4<<<(xn4 + 255) / 256, 256, 0, stream>>>(x, xb, xn4);
    k_wt<<<(IN_C * HID + 255) / 256, 256, 0, stream>>>(enc_w, enc_t, IN_C, HID);
    for (int l = 0; l < NLAYER; ++l)
        k_wt<<<(HID * HID + 255) / 256, 256, 0, stream>>>(
            conv_w + (size_t)l * HID * HID, conv_t + (size_t)l * HID * HID, HID, HID);
    k_wt<<<(HID * (HID / 2) + 255) / 256, 256, 0, stream>>>(w1, lin1_t, HID, HID / 2);

    // encoder: h0 = bf16(x @ enc_w + enc_b)  -- UNSCALED; conv GEMM applies dis[row]
    {
        dim3 g((N_NODES + 127) / 128, HID / 128);
        k_mm<0><<<g, 256, 0, stream>>>(xb, enc_t, enc_b, nullptr, hb, N_NODES, IN_C, HID);
    }

    for (int l = 0; l < NLAYER; ++l) {
        dim3 g((N_NODES + 127) / 128, HID / 128);
        // hw = (h @ conv_w[l]) * dis[row]  (source pre-scale for the gather)
        k_mm<1><<<g, 256, 0, stream>>>(hb, conv_t + (size_t)l * HID * HID, nullptr, dis,
                                       hw, N_NODES, HID, HID);
        k_agg<<<(N_NODES * 64 + 255) / 256, 256, 0, stream>>>(
            hw, srcl, offs, dis, conv_b + l * HID, ln_g + l * HID, ln_b + l * HID, hb, N_NODES);
    }

    // fused head: out = relu(h@w1+b1)@w2 + b2
    k_head<<<(N_NODES + 127) / 128, 256, 0, stream>>>(hb, lin1_t, b1, w2, b2, out, N_NODES);
}

// Round 7
// 833.181 us; speedup vs baseline: 1.9687x; 1.2583x over previous
//
#include <hip/hip_runtime.h>

#define N_NODES 100000
#define N_EDGES 1600000
#define IN_C    128
#define HID     256
#define NLAYER  4

#define NBUCK 391     // ceil(N_NODES / 256) buckets, bucket = col >> 8
#define BCAP  8192    // padded per-bucket capacity in pairs buffer (mean ~4090, +32 sigma safe)
#define EPB   4096    // edges per kb_scatter block
#define CAPL  6144    // per-bucket LDS srcl capacity in kb_build

typedef __attribute__((ext_vector_type(8))) __bf16 bf16x8;
typedef __attribute__((ext_vector_type(4))) float  floatx4;

__device__ inline unsigned short f2b(float f) {
    unsigned u = __builtin_bit_cast(unsigned, f);
    return (unsigned short)((u + 0x7fffu + ((u >> 16) & 1u)) >> 16);
}
__device__ inline float b2f(unsigned short s) {
    unsigned u = ((unsigned)s) << 16;
    return __builtin_bit_cast(float, u);
}
// unpack+accumulate 8 bf16 (uint4) into fp32[8]
__device__ inline void acc8(float* a, uint4 v) {
    unsigned wds[4] = {v.x, v.y, v.z, v.w};
    #pragma unroll
    for (int k = 0; k < 4; ++k) {
        a[2*k]   += __builtin_bit_cast(float, wds[k] << 16);
        a[2*k+1] += __builtin_bit_cast(float, wds[k] & 0xffff0000u);
    }
}

// ---------------- CSR build: bucket pipeline ----------------
__global__ void kb_zero(int* g, int m) {
    int i = blockIdx.x * blockDim.x + threadIdx.x;
    if (i < m) g[i] = 0;
}

// stage 4096 edges in LDS, local histogram, block-chunk reservation, chunked write to padded buckets
__global__ __launch_bounds__(256) void kb_scatter(
        const int* __restrict__ row, const int* __restrict__ col,
        int* __restrict__ gfill, uint2* __restrict__ pairs, int e) {
    __shared__ uint2 ep[EPB];
    __shared__ int hist[NBUCK];
    __shared__ int lbase[NBUCK];
    const int tid  = threadIdx.x;
    const int base = blockIdx.x * EPB;
    for (int b = tid; b < NBUCK; b += 256) hist[b] = 0;
    __syncthreads();
    #pragma unroll
    for (int k = 0; k < EPB / 256; ++k) {
        int i = base + k * 256 + tid;
        uint2 pr = make_uint2(0xffffffffu, 0u);
        if (i < e) {
            pr.x = (unsigned)col[i];
            pr.y = (unsigned)row[i];
            atomicAdd(&hist[pr.x >> 8], 1);
        }
        ep[k * 256 + tid] = pr;
    }
    __syncthreads();
    for (int b = tid; b < NBUCK; b += 256) {
        int h = hist[b];
        lbase[b] = h ? atomicAdd(&gfill[b], h) : 0;
    }
    __syncthreads();
    for (int b = tid; b < NBUCK; b += 256) hist[b] = 0;
    __syncthreads();
    #pragma unroll
    for (int k = 0; k < EPB / 256; ++k) {
        uint2 pr = ep[k * 256 + tid];
        if (pr.x != 0xffffffffu) {
            int bk = pr.x >> 8;
            int p  = lbase[bk] + atomicAdd(&hist[bk], 1);
            if (p < BCAP) pairs[(size_t)bk * BCAP + p] = pr;
        }
    }
}

// exclusive scan of gfill[NBUCK] -> boff[NBUCK+1]; also writes offs[N_NODES]=E
__global__ void kb_scan(const int* __restrict__ gfill, int* __restrict__ boff,
                        int* __restrict__ offs) {
    __shared__ int wsum[8];
    const int t = threadIdx.x, lane = t & 63, w = t >> 6;   // 512 threads
    int v = (t < NBUCK) ? gfill[t] : 0;
    int inc = v;
    #pragma unroll
    for (int o = 1; o < 64; o <<= 1) { int u = __shfl_up(inc, o); if (lane >= o) inc += u; }
    if (lane == 63) wsum[w] = inc;
    __syncthreads();
    if (t == 0) { int r = 0; for (int i = 0; i < 8; ++i) { int x = wsum[i]; wsum[i] = r; r += x; } }
    __syncthreads();
    int excl = wsum[w] + inc - v;
    if (t <= NBUCK) boff[t] = excl;
    if (t == 0) offs[N_NODES] = N_EDGES;
}

// one block per bucket: per-node count/scan in LDS; emit dis, offs, coalesced srcl
__global__ __launch_bounds__(256) void kb_build(
        const uint2* __restrict__ pairs, const int* __restrict__ gfill,
        const int* __restrict__ boff,
        int* __restrict__ offs, float* __restrict__ dis,
        int* __restrict__ srcl, int n) {
    __shared__ int lcnt[256];
    __shared__ int lstart[256];
    __shared__ int wsum[4];
    __shared__ int sl[CAPL];
    const int b = blockIdx.x;
    const int tid = threadIdx.x, lane = tid & 63, w = tid >> 6;
    int cnt = gfill[b]; if (cnt > CAPL) cnt = CAPL;
    const int base = boff[b];
    const uint2* bp = pairs + (size_t)b * BCAP;
    lcnt[tid] = 0;
    __syncthreads();
    for (int i = tid; i < cnt; i += 256)
        atomicAdd(&lcnt[bp[i].x & 255], 1);
    __syncthreads();
    int v = lcnt[tid];
    int inc = v;
    #pragma unroll
    for (int o = 1; o < 64; o <<= 1) { int u = __shfl_up(inc, o); if (lane >= o) inc += u; }
    if (lane == 63) wsum[w] = inc;
    __syncthreads();
    if (tid == 0) { int r = 0; for (int i = 0; i < 4; ++i) { int x = wsum[i]; wsum[i] = r; r += x; } }
    __syncthreads();
    int excl = wsum[w] + inc - v;
    lstart[tid] = excl;
    int node = (b << 8) + tid;
    if (node < n) {
        dis[node]  = rsqrtf((float)(v + 1));   // +1 self-loop
        offs[node] = base + excl;
    }
    __syncthreads();
    lcnt[tid] = 0;   // reuse as fill counters
    __syncthreads();
    for (int i = tid; i < cnt; i += 256) {
        uint2 pr = bp[i];
        int c = pr.x & 255;
        int q = lstart[c] + atomicAdd(&lcnt[c], 1);
        sl[q] = (int)pr.y;
    }
    __syncthreads();
    for (int i = tid; i < cnt; i += 256)
        srcl[base + i] = sl[i];
}

// ---------------- conversions ----------------
__global__ void k_f2b4(const float* __restrict__ src, unsigned short* __restrict__ dst, int n4) {
    int i = blockIdx.x * blockDim.x + threadIdx.x;
    if (i < n4) {
        float4 v = ((const float4*)src)[i];
        ushort4 o;
        o.x = f2b(v.x); o.y = f2b(v.y); o.z = f2b(v.z); o.w = f2b(v.w);
        ((ushort4*)dst)[i] = o;
    }
}

// W [K][Nn] fp32 row-major  ->  Wt [Nn][K] bf16
__global__ void k_wt(const float* __restrict__ W, unsigned short* __restrict__ Wt, int K, int Nn) {
    int idx = blockIdx.x * blockDim.x + threadIdx.x;
    if (idx < K * Nn) {
        int k = idx / Nn, n = idx % Nn;
        Wt[n * K + k] = f2b(W[idx]);
    }
}

// ---------------- MFMA GEMM: C[M,Nn] = A[M,K](bf16) @ Wt[Nn,K](bf16)^T ----------------
// MODE 0: enc   (+bias, *scale[row] if scale, store bf16)
// MODE 1: conv  (*scale[row],                 store bf16)
template<int MODE>
__global__ __launch_bounds__(256) void k_mm(
        const unsigned short* __restrict__ A,
        const unsigned short* __restrict__ Wt,
        const float* __restrict__ bias, const float* __restrict__ scale,
        void* __restrict__ Cout, int M, int K, int Nn) {
    __shared__ unsigned short As[128 * 32];
    __shared__ unsigned short Bs[128 * 32];
    const int tid  = threadIdx.x;
    const int lane = tid & 63;
    const int w    = tid >> 6;
    const int bm   = blockIdx.x * 128;
    const int bn   = blockIdx.y * 128;

    const int i0 = tid, i1 = tid + 256;
    const int r0 = i0 >> 2, r1 = i1 >> 2;
    const int q0 = i0 & 3,  q1 = i1 & 3;
    const int a_off0 = min(bm + r0, M - 1) * K + q0 * 8;
    const int a_off1 = min(bm + r1, M - 1) * K + q1 * 8;
    const int b_off0 = (bn + r0) * K + q0 * 8;
    const int b_off1 = (bn + r1) * K + q1 * 8;

    uint4 ra0, ra1, rb0, rb1;
    floatx4 acc[4][4];
    #pragma unroll
    for (int i = 0; i < 4; ++i)
        #pragma unroll
        for (int j = 0; j < 4; ++j)
            acc[i][j] = (floatx4){0.f, 0.f, 0.f, 0.f};

    const int wm = (w & 1) * 64;
    const int wn = (w >> 1) * 64;
    const int fm = lane & 15;
    const int fq = (lane >> 4) * 8;

    ra0 = *(const uint4*)(A  + a_off0);
    ra1 = *(const uint4*)(A  + a_off1);
    rb0 = *(const uint4*)(Wt + b_off0);
    rb1 = *(const uint4*)(Wt + b_off1);

    const int KT = K >> 5;
    for (int kt = 0; kt < KT; ++kt) {
        ((uint4*)As)[i0] = ra0; ((uint4*)As)[i1] = ra1;
        ((uint4*)Bs)[i0] = rb0; ((uint4*)Bs)[i1] = rb1;
        __syncthreads();
        if (kt + 1 < KT) {
            int k0 = (kt + 1) << 5;
            ra0 = *(const uint4*)(A  + a_off0 + k0);
            ra1 = *(const uint4*)(A  + a_off1 + k0);
            rb0 = *(const uint4*)(Wt + b_off0 + k0);
            rb1 = *(const uint4*)(Wt + b_off1 + k0);
        }
        bf16x8 af[4], bfr[4];
        #pragma unroll
        for (int i = 0; i < 4; ++i)
            af[i] = *(const bf16x8*)(const void*)(As + (wm + i * 16 + fm) * 32 + fq);
        #pragma unroll
        for (int j = 0; j < 4; ++j)
            bfr[j] = *(const bf16x8*)(const void*)(Bs + (wn + j * 16 + fm) * 32 + fq);
        #pragma unroll
        for (int i = 0; i < 4; ++i)
            #pragma unroll
            for (int j = 0; j < 4; ++j)
                acc[i][j] = __builtin_amdgcn_mfma_f32_16x16x32_bf16(af[i], bfr[j], acc[i][j], 0, 0, 0);
        __syncthreads();
    }

    const int quad = lane >> 4;
    #pragma unroll
    for (int i = 0; i < 4; ++i) {
        #pragma unroll
        for (int r = 0; r < 4; ++r) {
            int row = bm + wm + i * 16 + quad * 4 + r;
            if (row >= M) continue;
            float sc = scale ? scale[row] : 1.f;
            #pragma unroll
            for (int j = 0; j < 4; ++j) {
                int colg = bn + wn + j * 16 + fm;
                float v = acc[i][j][r];
                if (MODE == 0) v += bias[colg];
                v *= sc;
                ((unsigned short*)Cout)[(size_t)row * Nn + colg] = f2b(v);
            }
        }
    }
}

// ---------------- fused head: out = relu(h@w1+b1)@w2 + b2, MFMA, BN=128=full width ----------------
__global__ __launch_bounds__(256) void k_head(
        const unsigned short* __restrict__ A,     // h bf16 [M,256]
        const unsigned short* __restrict__ Wt,    // lin1^T bf16 [128][256]
        const float* __restrict__ b1, const float* __restrict__ w2,
        const float* __restrict__ b2, float* __restrict__ out, int M) {
    const int K = 256;
    __shared__ unsigned short As[128 * 32];
    __shared__ unsigned short Bs[128 * 32];
    const int tid  = threadIdx.x;
    const int lane = tid & 63;
    const int w    = tid >> 6;
    const int bm   = blockIdx.x * 128;

    const int i0 = tid, i1 = tid + 256;
    const int r0 = i0 >> 2, r1 = i1 >> 2;
    const int q0 = i0 & 3,  q1 = i1 & 3;
    const int a_off0 = min(bm + r0, M - 1) * K + q0 * 8;
    const int a_off1 = min(bm + r1, M - 1) * K + q1 * 8;
    const int b_off0 = r0 * K + q0 * 8;
    const int b_off1 = r1 * K + q1 * 8;

    uint4 ra0, ra1, rb0, rb1;
    floatx4 acc[4][4];
    #pragma unroll
    for (int i = 0; i < 4; ++i)
        #pragma unroll
        for (int j = 0; j < 4; ++j)
            acc[i][j] = (floatx4){0.f, 0.f, 0.f, 0.f};

    const int wm = (w & 1) * 64;
    const int wn = (w >> 1) * 64;
    const int fm = lane & 15;
    const int fq = (lane >> 4) * 8;

    ra0 = *(const uint4*)(A  + a_off0);
    ra1 = *(const uint4*)(A  + a_off1);
    rb0 = *(const uint4*)(Wt + b_off0);
    rb1 = *(const uint4*)(Wt + b_off1);

    for (int kt = 0; kt < 8; ++kt) {
        ((uint4*)As)[i0] = ra0; ((uint4*)As)[i1] = ra1;
        ((uint4*)Bs)[i0] = rb0; ((uint4*)Bs)[i1] = rb1;
        __syncthreads();
        if (kt + 1 < 8) {
            int k0 = (kt + 1) << 5;
            ra0 = *(const uint4*)(A  + a_off0 + k0);
            ra1 = *(const uint4*)(A  + a_off1 + k0);
            rb0 = *(const uint4*)(Wt + b_off0 + k0);
            rb1 = *(const uint4*)(Wt + b_off1 + k0);
        }
        bf16x8 af[4], bfr[4];
        #pragma unroll
        for (int i = 0; i < 4; ++i)
            af[i] = *(const bf16x8*)(const void*)(As + (wm + i * 16 + fm) * 32 + fq);
        #pragma unroll
        for (int j = 0; j < 4; ++j)
            bfr[j] = *(const bf16x8*)(const void*)(Bs + (wn + j * 16 + fm) * 32 + fq);
        #pragma unroll
        for (int i = 0; i < 4; ++i)
            #pragma unroll
            for (int j = 0; j < 4; ++j)
                acc[i][j] = __builtin_amdgcn_mfma_f32_16x16x32_bf16(af[i], bfr[j], acc[i][j], 0, 0, 0);
        __syncthreads();
    }

    // epilogue: relu(acc + b1) dot w2, reduce into out
    float* red = (float*)As;   // 256 floats, safe after final barrier
    const int q = lane >> 4;
    float b1v[4], w2v[4];
    #pragma unroll
    for (int j = 0; j < 4; ++j) {
        int col = wn + j * 16 + fm;
        b1v[j] = b1[col]; w2v[j] = w2[col];
    }
    #pragma unroll
    for (int i = 0; i < 4; ++i) {
        #pragma unroll
        for (int r = 0; r < 4; ++r) {
            float s = 0.f;
            #pragma unroll
            for (int j = 0; j < 4; ++j)
                s += fmaxf(acc[i][j][r] + b1v[j], 0.f) * w2v[j];
            #pragma unroll
            for (int off = 1; off < 16; off <<= 1) s += __shfl_xor(s, off);
            if (fm == 0) {
                int m = wm + i * 16 + q * 4 + r;
                red[m * 2 + (wn >> 6)] = s;
            }
        }
    }
    __syncthreads();
    if (tid < 128) {
        int row = bm + tid;
        if (row < M) out[row] = red[tid * 2] + red[tid * 2 + 1] + b2[0];
    }
}

// ---------------- aggregation + bias + LayerNorm + ReLU, one wave per node ----------------
// 2 edges per wave (lanes 0-31 / 32-63), 16B/lane; node uniform -> scalar index loads; 8-edge unroll
__global__ void k_agg(const unsigned short* __restrict__ hw, const int* __restrict__ srcl,
                      const int* __restrict__ offs, const float* __restrict__ dis,
                      const float* __restrict__ cb, const float* __restrict__ g,
                      const float* __restrict__ bt, unsigned short* __restrict__ hout, int n) {
    int gtid = blockIdx.x * blockDim.x + threadIdx.x;
    int node = __builtin_amdgcn_readfirstlane(gtid >> 6);   // grid sized so node < n always
    int lane = threadIdx.x & 63;
    const int half = lane >> 5;
    const int sub  = lane & 31;
    const uint4* T = (const uint4*)hw;    // row = 32 x uint4 (512 B)

    float a[8] = {0,0,0,0,0,0,0,0};
    float c[8] = {0,0,0,0,0,0,0,0};
    if (half == 0) {
        uint4 v = T[(size_t)node * 32 + sub];   // self-loop (pre-scaled by dis[src])
        acc8(a, v);
    }
    int p = offs[node], pe = offs[node + 1];
    for (; p + 7 < pe; p += 8) {
        int s0 = srcl[p],     s1 = srcl[p + 1], s2 = srcl[p + 2], s3 = srcl[p + 3];
        int s4 = srcl[p + 4], s5 = srcl[p + 5], s6 = srcl[p + 6], s7 = srcl[p + 7];
        int ea = half ? s1 : s0;
        int eb = half ? s3 : s2;
        int ec = half ? s5 : s4;
        int ed = half ? s7 : s6;
        uint4 va = T[(size_t)ea * 32 + sub];
        uint4 vb = T[(size_t)eb * 32 + sub];
        uint4 vc = T[(size_t)ec * 32 + sub];
        uint4 vd = T[(size_t)ed * 32 + sub];
        acc8(a, va);
        acc8(c, vb);
        acc8(a, vc);
        acc8(c, vd);
    }
    for (; p + 1 < pe; p += 2) {
        int s0 = srcl[p], s1 = srcl[p + 1];
        int ea = half ? s1 : s0;
        uint4 v = T[(size_t)ea * 32 + sub];
        acc8(a, v);
    }
    if (p < pe && half == 0) {
        int s0 = srcl[p];
        uint4 v = T[(size_t)s0 * 32 + sub];
        acc8(a, v);
    }
    #pragma unroll
    for (int j = 0; j < 8; ++j) {
        a[j] += c[j];
        a[j] += __shfl_xor(a[j], 32);   // combine edge-parity halves
    }
    // lanes 0-31 (and duplicated 32-63) now hold the full aggregate; features f = sub*8+j
    float dc = dis[node];
    const float4* cb4 = (const float4*)cb;
    const float4* g4  = (const float4*)g;
    const float4* bt4 = (const float4*)bt;
    float4 cba = cb4[sub * 2], cbb = cb4[sub * 2 + 1];
    float h[8];
    h[0] = fmaf(a[0], dc, cba.x); h[1] = fmaf(a[1], dc, cba.y);
    h[2] = fmaf(a[2], dc, cba.z); h[3] = fmaf(a[3], dc, cba.w);
    h[4] = fmaf(a[4], dc, cbb.x); h[5] = fmaf(a[5], dc, cbb.y);
    h[6] = fmaf(a[6], dc, cbb.z); h[7] = fmaf(a[7], dc, cbb.w);
    float s = 0.f, sq = 0.f;
    #pragma unroll
    for (int j = 0; j < 8; ++j) { s += h[j]; sq += h[j] * h[j]; }
    #pragma unroll
    for (int off = 1; off < 32; off <<= 1) { s += __shfl_xor(s, off); sq += __shfl_xor(sq, off); }
    float mu  = s * (1.f / 256.f);
    float var = sq * (1.f / 256.f) - mu * mu;
    float inv = rsqrtf(var + 1e-5f);
    if (half == 0) {
        float4 ga = g4[sub * 2], gb = g4[sub * 2 + 1];
        float4 ba = bt4[sub * 2], bb = bt4[sub * 2 + 1];
        float gv[8] = {ga.x, ga.y, ga.z, ga.w, gb.x, gb.y, gb.z, gb.w};
        float bv[8] = {ba.x, ba.y, ba.z, ba.w, bb.x, bb.y, bb.z, bb.w};
        unsigned short o[8];
        #pragma unroll
        for (int j = 0; j < 8; ++j)
            o[j] = f2b(fmaxf(fmaf((h[j] - mu) * inv, gv[j], bv[j]), 0.f));
        uint4 st;
        st.x = (unsigned)o[0] | ((unsigned)o[1] << 16);
        st.y = (unsigned)o[2] | ((unsigned)o[3] << 16);
        st.z = (unsigned)o[4] | ((unsigned)o[5] << 16);
        st.w = (unsigned)o[6] | ((unsigned)o[7] << 16);
        ((uint4*)hout)[(size_t)node * 32 + sub] = st;
    }
}

extern "C" void kernel_launch(void* const* d_in, const int* in_sizes, int n_in,
                              void* d_out, int out_size, void* d_ws, size_t ws_size,
                              hipStream_t stream) {
    const float* x      = (const float*)d_in[0];
    const int*   ei     = (const int*)d_in[1];     // (2,E) int32
    const float* enc_w  = (const float*)d_in[2];
    const float* enc_b  = (const float*)d_in[3];
    const float* conv_w = (const float*)d_in[4];
    const float* conv_b = (const float*)d_in[5];
    const float* ln_g   = (const float*)d_in[6];
    const float* ln_b   = (const float*)d_in[7];
    const float* w1     = (const float*)d_in[8];
    const float* b1     = (const float*)d_in[9];
    const float* w2     = (const float*)d_in[10];
    const float* b2     = (const float*)d_in[11];
    float* out = (float*)d_out;

    char* ws = (char*)d_ws;
    size_t off = 0;
    auto alloc = [&](size_t bytes) -> void* {
        void* p = ws + off;
        off = (off + bytes + 255) & ~(size_t)255;
        return p;
    };
    int*   offs  = (int*)alloc((size_t)(N_NODES + 1) * 4);
    int*   srcl  = (int*)alloc((size_t)N_EDGES * 4);
    float* dis   = (float*)alloc((size_t)N_NODES * 4);
    int*   gfill = (int*)alloc((size_t)NBUCK * 4);
    int*   boff  = (int*)alloc((size_t)(NBUCK + 1) * 4);
    unsigned short* hb = (unsigned short*)alloc((size_t)N_NODES * HID * 2);   // h, bf16
    unsigned short* hw = (unsigned short*)alloc((size_t)N_NODES * HID * 2);   // hw, bf16
    // overlay: pairs (CSR build) then xb (bf16 x) — lifetimes disjoint
    size_t pairs_bytes = (size_t)NBUCK * BCAP * 8;
    size_t xb_bytes    = (size_t)N_NODES * IN_C * 2;
    char* R3 = (char*)alloc(pairs_bytes > xb_bytes ? pairs_bytes : xb_bytes);
    uint2*          pairs = (uint2*)R3;
    unsigned short* xb    = (unsigned short*)R3;
    unsigned short* enc_t  = (unsigned short*)alloc((size_t)IN_C * HID * 2);
    unsigned short* conv_t = (unsigned short*)alloc((size_t)NLAYER * HID * HID * 2);
    unsigned short* lin1_t = (unsigned short*)alloc((size_t)HID * (HID / 2) * 2);

    const int* row = ei;             // sources
    const int* col = ei + N_EDGES;   // targets

    // ---- CSR build (bucket pipeline) ----
    kb_zero<<<(NBUCK + 255) / 256, 256, 0, stream>>>(gfill, NBUCK);
    kb_scatter<<<(N_EDGES + EPB - 1) / EPB, 256, 0, stream>>>(row, col, gfill, pairs, N_EDGES);
    kb_scan<<<1, 512, 0, stream>>>(gfill, boff, offs);
    kb_build<<<NBUCK, 256, 0, stream>>>(pairs, gfill, boff, offs, dis, srcl, N_NODES);

    // ---- conversions ----
    int xn4 = N_NODES * IN_C / 4;
    k_f2b4<<<(xn4 + 255) / 256, 256, 0, stream>>>(x, xb, xn4);
    k_wt<<<(IN_C * HID + 255) / 256, 256, 0, stream>>>(enc_w, enc_t, IN_C, HID);
    for (int l = 0; l < NLAYER; ++l)
        k_wt<<<(HID * HID + 255) / 256, 256, 0, stream>>>(
            conv_w + (size_t)l * HID * HID, conv_t + (size_t)l * HID * HID, HID, HID);
    k_wt<<<(HID * (HID / 2) + 255) / 256, 256, 0, stream>>>(w1, lin1_t, HID, HID / 2);

    // encoder: h0 = bf16(x @ enc_w + enc_b)  -- unscaled; conv GEMM applies dis[row]
    {
        dim3 g((N_NODES + 127) / 128, HID / 128);
        k_mm<0><<<g, 256, 0, stream>>>(xb, enc_t, enc_b, nullptr, hb, N_NODES, IN_C, HID);
    }

    for (int l = 0; l < NLAYER; ++l) {
        dim3 g((N_NODES + 127) / 128, HID / 128);
        // hw = (h @ conv_w[l]) * dis[row]  (source pre-scale for the gather)
        k_mm<1><<<g, 256, 0, stream>>>(hb, conv_t + (size_t)l * HID * HID, nullptr, dis,
                                       hw, N_NODES, HID, HID);
        k_agg<<<(N_NODES * 64 + 255) / 256, 256, 0, stream>>>(
            hw, srcl, offs, dis, conv_b + l * HID, ln_g + l * HID, ln_b + l * HID, hb, N_NODES);
    }

    // fused head: out = relu(h@w1+b1)@w2 + b2
    k_head<<<(N_NODES + 127) / 128, 256, 0, stream>>>(hb, lin1_t, b1, w2, b2, out, N_NODES);
}

// Round 8
// 827.196 us; speedup vs baseline: 1.9830x; 1.0072x over previous
//
#include <hip/hip_runtime.h>

#define N_NODES 100000
#define N_EDGES 1600000
#define IN_C    128
#define HID     256
#define NLAYER  4

#define NBUCK 391     // ceil(N_NODES / 256) buckets, bucket = col >> 8
#define BCAP  8192    // padded per-bucket capacity in pairs buffer
#define EPB   4096    // edges per kb_scatter block
#define CAPL  6144    // per-bucket LDS srcl capacity in kb_build

typedef __attribute__((ext_vector_type(8))) __bf16 bf16x8;
typedef __attribute__((ext_vector_type(4))) float  floatx4;
typedef __attribute__((ext_vector_type(2))) float  floatx2;

__device__ inline unsigned short f2b(float f) {
    unsigned u = __builtin_bit_cast(unsigned, f);
    return (unsigned short)((u + 0x7fffu + ((u >> 16) & 1u)) >> 16);
}
// packed accumulate: 8 bf16 (uint4) into 4 x floatx2 (lo,hi per word) -> v_pk_add_f32
__device__ inline void acc8p(floatx2* a, uint4 v) {
    unsigned wds[4] = {v.x, v.y, v.z, v.w};
    #pragma unroll
    for (int k = 0; k < 4; ++k) {
        floatx2 t;
        t.x = __builtin_bit_cast(float, wds[k] << 16);
        t.y = __builtin_bit_cast(float, wds[k] & 0xffff0000u);
        a[k] += t;
    }
}

// ---------------- CSR build: bucket pipeline ----------------
__global__ void kb_zero(int* g, int m) {
    int i = blockIdx.x * blockDim.x + threadIdx.x;
    if (i < m) g[i] = 0;
}

__global__ __launch_bounds__(256) void kb_scatter(
        const int* __restrict__ row, const int* __restrict__ col,
        int* __restrict__ gfill, uint2* __restrict__ pairs, int e) {
    __shared__ uint2 ep[EPB];
    __shared__ int hist[NBUCK];
    __shared__ int lbase[NBUCK];
    const int tid  = threadIdx.x;
    const int base = blockIdx.x * EPB;
    for (int b = tid; b < NBUCK; b += 256) hist[b] = 0;
    __syncthreads();
    #pragma unroll
    for (int k = 0; k < EPB / 256; ++k) {
        int i = base + k * 256 + tid;
        uint2 pr = make_uint2(0xffffffffu, 0u);
        if (i < e) {
            pr.x = (unsigned)col[i];
            pr.y = (unsigned)row[i];
            atomicAdd(&hist[pr.x >> 8], 1);
        }
        ep[k * 256 + tid] = pr;
    }
    __syncthreads();
    for (int b = tid; b < NBUCK; b += 256) {
        int h = hist[b];
        lbase[b] = h ? atomicAdd(&gfill[b], h) : 0;
    }
    __syncthreads();
    for (int b = tid; b < NBUCK; b += 256) hist[b] = 0;
    __syncthreads();
    #pragma unroll
    for (int k = 0; k < EPB / 256; ++k) {
        uint2 pr = ep[k * 256 + tid];
        if (pr.x != 0xffffffffu) {
            int bk = pr.x >> 8;
            int p  = lbase[bk] + atomicAdd(&hist[bk], 1);
            if (p < BCAP) pairs[(size_t)bk * BCAP + p] = pr;
        }
    }
}

__global__ void kb_scan(const int* __restrict__ gfill, int* __restrict__ boff,
                        int* __restrict__ offs) {
    __shared__ int wsum[8];
    const int t = threadIdx.x, lane = t & 63, w = t >> 6;   // 512 threads
    int v = (t < NBUCK) ? gfill[t] : 0;
    int inc = v;
    #pragma unroll
    for (int o = 1; o < 64; o <<= 1) { int u = __shfl_up(inc, o); if (lane >= o) inc += u; }
    if (lane == 63) wsum[w] = inc;
    __syncthreads();
    if (t == 0) { int r = 0; for (int i = 0; i < 8; ++i) { int x = wsum[i]; wsum[i] = r; r += x; } }
    __syncthreads();
    int excl = wsum[w] + inc - v;
    if (t <= NBUCK) boff[t] = excl;
    if (t == 0) offs[N_NODES] = N_EDGES;
}

__global__ __launch_bounds__(256) void kb_build(
        const uint2* __restrict__ pairs, const int* __restrict__ gfill,
        const int* __restrict__ boff,
        int* __restrict__ offs, float* __restrict__ dis,
        int* __restrict__ srcl, int n) {
    __shared__ int lcnt[256];
    __shared__ int lstart[256];
    __shared__ int wsum[4];
    __shared__ int sl[CAPL];
    const int b = blockIdx.x;
    const int tid = threadIdx.x, lane = tid & 63, w = tid >> 6;
    int cnt = gfill[b]; if (cnt > CAPL) cnt = CAPL;
    const int base = boff[b];
    const uint2* bp = pairs + (size_t)b * BCAP;
    lcnt[tid] = 0;
    __syncthreads();
    for (int i = tid; i < cnt; i += 256)
        atomicAdd(&lcnt[bp[i].x & 255], 1);
    __syncthreads();
    int v = lcnt[tid];
    int inc = v;
    #pragma unroll
    for (int o = 1; o < 64; o <<= 1) { int u = __shfl_up(inc, o); if (lane >= o) inc += u; }
    if (lane == 63) wsum[w] = inc;
    __syncthreads();
    if (tid == 0) { int r = 0; for (int i = 0; i < 4; ++i) { int x = wsum[i]; wsum[i] = r; r += x; } }
    __syncthreads();
    int excl = wsum[w] + inc - v;
    lstart[tid] = excl;
    int node = (b << 8) + tid;
    if (node < n) {
        dis[node]  = rsqrtf((float)(v + 1));   // +1 self-loop
        offs[node] = base + excl;
    }
    __syncthreads();
    lcnt[tid] = 0;   // reuse as fill counters
    __syncthreads();
    for (int i = tid; i < cnt; i += 256) {
        uint2 pr = bp[i];
        int c = pr.x & 255;
        int q = lstart[c] + atomicAdd(&lcnt[c], 1);
        sl[q] = (int)pr.y;
    }
    __syncthreads();
    for (int i = tid; i < cnt; i += 256)
        srcl[base + i] = sl[i];
}

// ---------------- merged weight transpose+convert: all three weight sets ----------------
// enc_w [128,256] -> enc_t [256][128]; conv_w[l][256,256] -> conv_t[l][256][256];
// w1 [256,128] -> lin1_t [128][256]
__global__ void k_wt_all(const float* __restrict__ enc_w, const float* __restrict__ conv_w,
                         const float* __restrict__ w1,
                         unsigned short* __restrict__ enc_t, unsigned short* __restrict__ conv_t,
                         unsigned short* __restrict__ lin1_t) {
    int idx = blockIdx.x * blockDim.x + threadIdx.x;
    if (idx < IN_C * HID) {
        int k = idx / HID, n = idx % HID;
        enc_t[n * IN_C + k] = f2b(enc_w[idx]);
    } else if (idx < IN_C * HID + NLAYER * HID * HID) {
        int r = idx - IN_C * HID;
        int l = r / (HID * HID);
        int e = r % (HID * HID);
        int k = e / HID, n = e % HID;
        conv_t[(size_t)l * HID * HID + n * HID + k] = f2b(conv_w[r]);
    } else if (idx < IN_C * HID + NLAYER * HID * HID + HID * (HID / 2)) {
        int e = idx - (IN_C * HID + NLAYER * HID * HID);
        int k = e / (HID / 2), n = e % (HID / 2);
        lin1_t[n * HID + k] = f2b(w1[e]);
    }
}

// ---------------- MFMA GEMM: C[M,Nn] = A[M,K] @ Wt[Nn,K]^T ----------------
// MODE 0: enc  (A fp32, +bias,        store bf16)
// MODE 1: conv (A bf16, *scale[row],  store bf16)
template<int MODE>
__global__ __launch_bounds__(256) void k_mm(
        const void* __restrict__ Ain,
        const unsigned short* __restrict__ Wt,
        const float* __restrict__ bias, const float* __restrict__ scale,
        void* __restrict__ Cout, int M, int K, int Nn) {
    __shared__ unsigned short As[128 * 32];
    __shared__ unsigned short Bs[128 * 32];
    const int tid  = threadIdx.x;
    const int lane = tid & 63;
    const int w    = tid >> 6;
    const int bm   = blockIdx.x * 128;
    const int bn   = blockIdx.y * 128;

    const int i0 = tid, i1 = tid + 256;
    const int r0 = i0 >> 2, r1 = i1 >> 2;
    const int q0 = i0 & 3,  q1 = i1 & 3;
    const int a_off0 = min(bm + r0, M - 1) * K + q0 * 8;
    const int a_off1 = min(bm + r1, M - 1) * K + q1 * 8;
    const int b_off0 = (bn + r0) * K + q0 * 8;
    const int b_off1 = (bn + r1) * K + q1 * 8;

    floatx4 acc[4][4];
    #pragma unroll
    for (int i = 0; i < 4; ++i)
        #pragma unroll
        for (int j = 0; j < 4; ++j)
            acc[i][j] = (floatx4){0.f, 0.f, 0.f, 0.f};

    const int wm = (w & 1) * 64;
    const int wn = (w >> 1) * 64;
    const int fm = lane & 15;
    const int fq = (lane >> 4) * 8;

    const unsigned short* Ab = (const unsigned short*)Ain;
    const float*          Af = (const float*)Ain;

    uint4 ra0, ra1, rb0, rb1;
    auto loadA = [&](int koff, uint4& oa0, uint4& oa1) {
        if (MODE == 0) {
            float4 f0 = *(const float4*)(Af + a_off0 + koff);
            float4 f1 = *(const float4*)(Af + a_off0 + koff + 4);
            oa0.x = (unsigned)f2b(f0.x) | ((unsigned)f2b(f0.y) << 16);
            oa0.y = (unsigned)f2b(f0.z) | ((unsigned)f2b(f0.w) << 16);
            oa0.z = (unsigned)f2b(f1.x) | ((unsigned)f2b(f1.y) << 16);
            oa0.w = (unsigned)f2b(f1.z) | ((unsigned)f2b(f1.w) << 16);
            float4 g0 = *(const float4*)(Af + a_off1 + koff);
            float4 g1 = *(const float4*)(Af + a_off1 + koff + 4);
            oa1.x = (unsigned)f2b(g0.x) | ((unsigned)f2b(g0.y) << 16);
            oa1.y = (unsigned)f2b(g0.z) | ((unsigned)f2b(g0.w) << 16);
            oa1.z = (unsigned)f2b(g1.x) | ((unsigned)f2b(g1.y) << 16);
            oa1.w = (unsigned)f2b(g1.z) | ((unsigned)f2b(g1.w) << 16);
        } else {
            oa0 = *(const uint4*)(Ab + a_off0 + koff);
            oa1 = *(const uint4*)(Ab + a_off1 + koff);
        }
    };

    loadA(0, ra0, ra1);
    rb0 = *(const uint4*)(Wt + b_off0);
    rb1 = *(const uint4*)(Wt + b_off1);

    const int KT = K >> 5;
    for (int kt = 0; kt < KT; ++kt) {
        ((uint4*)As)[i0] = ra0; ((uint4*)As)[i1] = ra1;
        ((uint4*)Bs)[i0] = rb0; ((uint4*)Bs)[i1] = rb1;
        __syncthreads();
        if (kt + 1 < KT) {
            int k0 = (kt + 1) << 5;
            loadA(k0, ra0, ra1);
            rb0 = *(const uint4*)(Wt + b_off0 + k0);
            rb1 = *(const uint4*)(Wt + b_off1 + k0);
        }
        bf16x8 af[4], bfr[4];
        #pragma unroll
        for (int i = 0; i < 4; ++i)
            af[i] = *(const bf16x8*)(const void*)(As + (wm + i * 16 + fm) * 32 + fq);
        #pragma unroll
        for (int j = 0; j < 4; ++j)
            bfr[j] = *(const bf16x8*)(const void*)(Bs + (wn + j * 16 + fm) * 32 + fq);
        #pragma unroll
        for (int i = 0; i < 4; ++i)
            #pragma unroll
            for (int j = 0; j < 4; ++j)
                acc[i][j] = __builtin_amdgcn_mfma_f32_16x16x32_bf16(af[i], bfr[j], acc[i][j], 0, 0, 0);
        __syncthreads();
    }

    const int quad = lane >> 4;
    #pragma unroll
    for (int i = 0; i < 4; ++i) {
        #pragma unroll
        for (int r = 0; r < 4; ++r) {
            int row = bm + wm + i * 16 + quad * 4 + r;
            if (row >= M) continue;
            float sc = scale ? scale[row] : 1.f;
            #pragma unroll
            for (int j = 0; j < 4; ++j) {
                int colg = bn + wn + j * 16 + fm;
                float v = acc[i][j][r];
                if (MODE == 0) v += bias[colg];
                v *= sc;
                ((unsigned short*)Cout)[(size_t)row * Nn + colg] = f2b(v);
            }
        }
    }
}

// ---------------- fused head: out = relu(h@w1+b1)@w2 + b2 ----------------
__global__ __launch_bounds__(256) void k_head(
        const unsigned short* __restrict__ A,     // h bf16 [M,256]
        const unsigned short* __restrict__ Wt,    // lin1^T bf16 [128][256]
        const float* __restrict__ b1, const float* __restrict__ w2,
        const float* __restrict__ b2, float* __restrict__ out, int M) {
    const int K = 256;
    __shared__ unsigned short As[128 * 32];
    __shared__ unsigned short Bs[128 * 32];
    const int tid  = threadIdx.x;
    const int lane = tid & 63;
    const int w    = tid >> 6;
    const int bm   = blockIdx.x * 128;

    const int i0 = tid, i1 = tid + 256;
    const int r0 = i0 >> 2, r1 = i1 >> 2;
    const int q0 = i0 & 3,  q1 = i1 & 3;
    const int a_off0 = min(bm + r0, M - 1) * K + q0 * 8;
    const int a_off1 = min(bm + r1, M - 1) * K + q1 * 8;
    const int b_off0 = r0 * K + q0 * 8;
    const int b_off1 = r1 * K + q1 * 8;

    uint4 ra0, ra1, rb0, rb1;
    floatx4 acc[4][4];
    #pragma unroll
    for (int i = 0; i < 4; ++i)
        #pragma unroll
        for (int j = 0; j < 4; ++j)
            acc[i][j] = (floatx4){0.f, 0.f, 0.f, 0.f};

    const int wm = (w & 1) * 64;
    const int wn = (w >> 1) * 64;
    const int fm = lane & 15;
    const int fq = (lane >> 4) * 8;

    ra0 = *(const uint4*)(A + a_off0);
    ra1 = *(const uint4*)(A + a_off1);
    rb0 = *(const uint4*)(Wt + b_off0);
    rb1 = *(const uint4*)(Wt + b_off1);

    for (int kt = 0; kt < 8; ++kt) {
        ((uint4*)As)[i0] = ra0; ((uint4*)As)[i1] = ra1;
        ((uint4*)Bs)[i0] = rb0; ((uint4*)Bs)[i1] = rb1;
        __syncthreads();
        if (kt + 1 < 8) {
            int k0 = (kt + 1) << 5;
            ra0 = *(const uint4*)(A + a_off0 + k0);
            ra1 = *(const uint4*)(A + a_off1 + k0);
            rb0 = *(const uint4*)(Wt + b_off0 + k0);
            rb1 = *(const uint4*)(Wt + b_off1 + k0);
        }
        bf16x8 af[4], bfr[4];
        #pragma unroll
        for (int i = 0; i < 4; ++i)
            af[i] = *(const bf16x8*)(const void*)(As + (wm + i * 16 + fm) * 32 + fq);
        #pragma unroll
        for (int j = 0; j < 4; ++j)
            bfr[j] = *(const bf16x8*)(const void*)(Bs + (wn + j * 16 + fm) * 32 + fq);
        #pragma unroll
        for (int i = 0; i < 4; ++i)
            #pragma unroll
            for (int j = 0; j < 4; ++j)
                acc[i][j] = __builtin_amdgcn_mfma_f32_16x16x32_bf16(af[i], bfr[j], acc[i][j], 0, 0, 0);
        __syncthreads();
    }

    float* red = (float*)As;
    const int q = lane >> 4;
    float b1v[4], w2v[4];
    #pragma unroll
    for (int j = 0; j < 4; ++j) {
        int col = wn + j * 16 + fm;
        b1v[j] = b1[col]; w2v[j] = w2[col];
    }
    #pragma unroll
    for (int i = 0; i < 4; ++i) {
        #pragma unroll
        for (int r = 0; r < 4; ++r) {
            float s = 0.f;
            #pragma unroll
            for (int j = 0; j < 4; ++j)
                s += fmaxf(acc[i][j][r] + b1v[j], 0.f) * w2v[j];
            #pragma unroll
            for (int off = 1; off < 16; off <<= 1) s += __shfl_xor(s, off);
            if (fm == 0) {
                int m = wm + i * 16 + q * 4 + r;
                red[m * 2 + (wn >> 6)] = s;
            }
        }
    }
    __syncthreads();
    if (tid < 128) {
        int row = bm + tid;
        if (row < M) out[row] = red[tid * 2] + red[tid * 2 + 1] + b2[0];
    }
}

// ---------------- aggregation + bias + LayerNorm + ReLU, one wave per node ----------------
// 2 edges per wave (lane halves), 16B/lane; scalar index loads; 16-edge unroll, packed adds
__global__ void k_agg(const unsigned short* __restrict__ hw, const int* __restrict__ srcl,
                      const int* __restrict__ offs, const float* __restrict__ dis,
                      const float* __restrict__ cb, const float* __restrict__ g,
                      const float* __restrict__ bt, unsigned short* __restrict__ hout, int n) {
    int gtid = blockIdx.x * blockDim.x + threadIdx.x;
    int node = __builtin_amdgcn_readfirstlane(gtid >> 6);   // grid sized so node < n always
    int lane = threadIdx.x & 63;
    const int half = lane >> 5;
    const int sub  = lane & 31;
    const uint4* T = (const uint4*)hw;    // row = 32 x uint4 (512 B)

    floatx2 A0[4], C0[4];
    #pragma unroll
    for (int k = 0; k < 4; ++k) { A0[k] = (floatx2){0.f, 0.f}; C0[k] = (floatx2){0.f, 0.f}; }
    if (half == 0) {
        uint4 v = T[(size_t)node * 32 + sub];   // self-loop (pre-scaled by dis[src])
        acc8p(A0, v);
    }
    int p = offs[node], pe = offs[node + 1];
    for (; p + 15 < pe; p += 16) {
        int s[16];
        #pragma unroll
        for (int t = 0; t < 16; ++t) s[t] = srcl[p + t];
        uint4 v0 = T[(size_t)(half ? s[1]  : s[0])  * 32 + sub];
        uint4 v1 = T[(size_t)(half ? s[3]  : s[2])  * 32 + sub];
        uint4 v2 = T[(size_t)(half ? s[5]  : s[4])  * 32 + sub];
        uint4 v3 = T[(size_t)(half ? s[7]  : s[6])  * 32 + sub];
        uint4 v4 = T[(size_t)(half ? s[9]  : s[8])  * 32 + sub];
        uint4 v5 = T[(size_t)(half ? s[11] : s[10]) * 32 + sub];
        uint4 v6 = T[(size_t)(half ? s[13] : s[12]) * 32 + sub];
        uint4 v7 = T[(size_t)(half ? s[15] : s[14]) * 32 + sub];
        acc8p(A0, v0); acc8p(C0, v1); acc8p(A0, v2); acc8p(C0, v3);
        acc8p(A0, v4); acc8p(C0, v5); acc8p(A0, v6); acc8p(C0, v7);
    }
    for (; p + 7 < pe; p += 8) {
        int s0 = srcl[p],     s1 = srcl[p + 1], s2 = srcl[p + 2], s3 = srcl[p + 3];
        int s4 = srcl[p + 4], s5 = srcl[p + 5], s6 = srcl[p + 6], s7 = srcl[p + 7];
        uint4 v0 = T[(size_t)(half ? s1 : s0) * 32 + sub];
        uint4 v1 = T[(size_t)(half ? s3 : s2) * 32 + sub];
        uint4 v2 = T[(size_t)(half ? s5 : s4) * 32 + sub];
        uint4 v3 = T[(size_t)(half ? s7 : s6) * 32 + sub];
        acc8p(A0, v0); acc8p(C0, v1); acc8p(A0, v2); acc8p(C0, v3);
    }
    for (; p + 1 < pe; p += 2) {
        int s0 = srcl[p], s1 = srcl[p + 1];
        uint4 v = T[(size_t)(half ? s1 : s0) * 32 + sub];
        acc8p(A0, v);
    }
    if (p < pe && half == 0) {
        uint4 v = T[(size_t)srcl[p] * 32 + sub];
        acc8p(A0, v);
    }
    float a[8];
    #pragma unroll
    for (int k = 0; k < 4; ++k) {
        floatx2 t = A0[k] + C0[k];
        a[2 * k]     = t.x + __shfl_xor(t.x, 32);
        a[2 * k + 1] = t.y + __shfl_xor(t.y, 32);
    }
    // lanes 0-31 (dup in 32-63) hold the aggregate; features f = sub*8+j
    float dc = dis[node];
    const float4* cb4 = (const float4*)cb;
    const float4* g4  = (const float4*)g;
    const float4* bt4 = (const float4*)bt;
    float4 cba = cb4[sub * 2], cbb = cb4[sub * 2 + 1];
    float h[8];
    h[0] = fmaf(a[0], dc, cba.x); h[1] = fmaf(a[1], dc, cba.y);
    h[2] = fmaf(a[2], dc, cba.z); h[3] = fmaf(a[3], dc, cba.w);
    h[4] = fmaf(a[4], dc, cbb.x); h[5] = fmaf(a[5], dc, cbb.y);
    h[6] = fmaf(a[6], dc, cbb.z); h[7] = fmaf(a[7], dc, cbb.w);
    float s = 0.f, sq = 0.f;
    #pragma unroll
    for (int j = 0; j < 8; ++j) { s += h[j]; sq += h[j] * h[j]; }
    #pragma unroll
    for (int off = 1; off < 32; off <<= 1) { s += __shfl_xor(s, off); sq += __shfl_xor(sq, off); }
    float mu  = s * (1.f / 256.f);
    float var = sq * (1.f / 256.f) - mu * mu;
    float inv = rsqrtf(var + 1e-5f);
    if (half == 0) {
        float4 ga = g4[sub * 2], gb = g4[sub * 2 + 1];
        float4 ba = bt4[sub * 2], bb = bt4[sub * 2 + 1];
        float gv[8] = {ga.x, ga.y, ga.z, ga.w, gb.x, gb.y, gb.z, gb.w};
        float bv[8] = {ba.x, ba.y, ba.z, ba.w, bb.x, bb.y, bb.z, bb.w};
        unsigned short o[8];
        #pragma unroll
        for (int j = 0; j < 8; ++j)
            o[j] = f2b(fmaxf(fmaf((h[j] - mu) * inv, gv[j], bv[j]), 0.f));
        uint4 st;
        st.x = (unsigned)o[0] | ((unsigned)o[1] << 16);
        st.y = (unsigned)o[2] | ((unsigned)o[3] << 16);
        st.z = (unsigned)o[4] | ((unsigned)o[5] << 16);
        st.w = (unsigned)o[6] | ((unsigned)o[7] << 16);
        ((uint4*)hout)[(size_t)node * 32 + sub] = st;
    }
}

extern "C" void kernel_launch(void* const* d_in, const int* in_sizes, int n_in,
                              void* d_out, int out_size, void* d_ws, size_t ws_size,
                              hipStream_t stream) {
    const float* x      = (const float*)d_in[0];
    const int*   ei     = (const int*)d_in[1];     // (2,E) int32
    const float* enc_w  = (const float*)d_in[2];
    const float* enc_b  = (const float*)d_in[3];
    const float* conv_w = (const float*)d_in[4];
    const float* conv_b = (const float*)d_in[5];
    const float* ln_g   = (const float*)d_in[6];
    const float* ln_b   = (const float*)d_in[7];
    const float* w1     = (const float*)d_in[8];
    const float* b1     = (const float*)d_in[9];
    const float* w2     = (const float*)d_in[10];
    const float* b2     = (const float*)d_in[11];
    float* out = (float*)d_out;

    char* ws = (char*)d_ws;
    size_t off = 0;
    auto alloc = [&](size_t bytes) -> void* {
        void* p = ws + off;
        off = (off + bytes + 255) & ~(size_t)255;
        return p;
    };
    int*   offs  = (int*)alloc((size_t)(N_NODES + 1) * 4);
    int*   srcl  = (int*)alloc((size_t)N_EDGES * 4);
    float* dis   = (float*)alloc((size_t)N_NODES * 4);
    int*   gfill = (int*)alloc((size_t)NBUCK * 4);
    int*   boff  = (int*)alloc((size_t)(NBUCK + 1) * 4);
    unsigned short* hb = (unsigned short*)alloc((size_t)N_NODES * HID * 2);   // h, bf16
    unsigned short* hw = (unsigned short*)alloc((size_t)N_NODES * HID * 2);   // hw, bf16
    uint2* pairs = (uint2*)alloc((size_t)NBUCK * BCAP * 8);
    unsigned short* enc_t  = (unsigned short*)alloc((size_t)IN_C * HID * 2);
    unsigned short* conv_t = (unsigned short*)alloc((size_t)NLAYER * HID * HID * 2);
    unsigned short* lin1_t = (unsigned short*)alloc((size_t)HID * (HID / 2) * 2);

    const int* row = ei;             // sources
    const int* col = ei + N_EDGES;   // targets

    // ---- CSR build (bucket pipeline) ----
    kb_zero<<<(NBUCK + 255) / 256, 256, 0, stream>>>(gfill, NBUCK);
    kb_scatter<<<(N_EDGES + EPB - 1) / EPB, 256, 0, stream>>>(row, col, gfill, pairs, N_EDGES);
    kb_scan<<<1, 512, 0, stream>>>(gfill, boff, offs);
    kb_build<<<NBUCK, 256, 0, stream>>>(pairs, gfill, boff, offs, dis, srcl, N_NODES);

    // ---- weight conversions (single kernel) ----
    {
        int tot = IN_C * HID + NLAYER * HID * HID + HID * (HID / 2);
        k_wt_all<<<(tot + 255) / 256, 256, 0, stream>>>(enc_w, conv_w, w1, enc_t, conv_t, lin1_t);
    }

    // encoder: h0 = bf16(x @ enc_w + enc_b)  (A read as fp32, converted in staging)
    {
        dim3 g((N_NODES + 127) / 128, HID / 128);
        k_mm<0><<<g, 256, 0, stream>>>(x, enc_t, enc_b, nullptr, hb, N_NODES, IN_C, HID);
    }

    for (int l = 0; l < NLAYER; ++l) {
        dim3 g((N_NODES + 127) / 128, HID / 128);
        // hw = (h @ conv_w[l]) * dis[row]  (source pre-scale for the gather)
        k_mm<1><<<g, 256, 0, stream>>>(hb, conv_t + (size_t)l * HID * HID, nullptr, dis,
                                       hw, N_NODES, HID, HID);
        k_agg<<<(N_NODES * 64 + 255) / 256, 256, 0, stream>>>(
            hw, srcl, offs, dis, conv_b + l * HID, ln_g + l * HID, ln_b + l * HID, hb, N_NODES);
    }

    // fused head: out = relu(h@w1+b1)@w2 + b2
    k_head<<<(N_NODES + 127) / 128, 256, 0, stream>>>(hb, lin1_t, b1, w2, b2, out, N_NODES);
}